// Round 4
// baseline (720.148 us; speedup 1.0000x reference)
//
#include <hip/hip_runtime.h>
#include <hip/hip_bf16.h>

typedef unsigned short u16;
typedef __attribute__((ext_vector_type(8))) short bf16x8;
typedef __attribute__((ext_vector_type(4))) float f32x4;

#define MFMA16(a,b,c) __builtin_amdgcn_mfma_f32_16x16x32_bf16((a),(b),(c),0,0,0)

__device__ __forceinline__ float bf2f(u16 u){ union{unsigned int i; float f;} v; v.i=((unsigned int)u)<<16; return v.f; }
__device__ __forceinline__ u16 f2bf(float f){ union{float f; unsigned int i;} v; v.f=f; unsigned int r=v.i+0x7fffu+((v.i>>16)&1u); return (u16)(r>>16); }
__device__ __forceinline__ unsigned int pk2(float a, float b){
  __hip_bfloat162 h = __float22bfloat162_rn(make_float2(a,b));
  union{ __hip_bfloat162 h; unsigned int u; } v; v.h = h; return v.u;
}

// ============ K0: fp32 -> bf16 conversions for the 3 MFMA weights, one launch ====
__global__ __launch_bounds__(256) void kcvt3(const float* __restrict__ WE, u16* __restrict__ WEb,
                                             const float* __restrict__ Wq, u16* __restrict__ Wqb,
                                             const float* __restrict__ Wo, u16* __restrict__ Wob){
  int bid = blockIdx.x;
  const float* src; u16* dst; int base;
  if(bid < 2048){ src = WE; dst = WEb; base = bid*1024; }
  else if(bid < 2112){ src = Wq; dst = Wqb; base = (bid-2048)*1024; }
  else { src = Wo; dst = Wob; base = (bid-2112)*1024; }
  int i = base + threadIdx.x*4;
  float4 v = *(const float4*)(src + i);
  ushort4 o; o.x = f2bf(v.x); o.y = f2bf(v.y); o.z = f2bf(v.z); o.w = f2bf(v.w);
  *(ushort4*)(dst + i) = o;
}

// ================= K1: qkvvT[b][oc][n] = sum_c Wq[oc][c]*x[b][c][n] (MFMA) =========
// + fused sumsq epilogue for q/k rows (oc<256): lm-group shfl reduce + 1 atomic
//   per 64 tokens. Replaces k2b's full 67 MB re-read of qkvvT.
#define K1PAD 136
__global__ __launch_bounds__(256) void k1_qkvv(const float* __restrict__ x, const u16* __restrict__ Wqb,
                                               u16* __restrict__ qkvvT, float* __restrict__ sumsq){
  __shared__ u16 lB[128*K1PAD];
  const int tile = blockIdx.x;            // b*256 + token tile
  const int b  = tile >> 8;
  const int n0 = (tile & 255) << 7;
  const int tid = threadIdx.x;
  const float* xb = x + (size_t)b*128*32768;
  {
    const int cb = (tid >> 4) << 1;       // even channel 0..30
    const int m  = tid & 15;
    const int t8 = m << 3;                // 8-token block
    const int swz = (m & 3) << 3;         // rotation amount (u16 units)
    unsigned int* basep = (unsigned int*)lB;
    #pragma unroll
    for(int r=0;r<4;++r){
      const int c = cb + (r<<5);
      const float4* p0 = (const float4*)(xb + (size_t)c*32768 + n0 + t8);
      const float4* p1 = (const float4*)(xb + (size_t)(c+1)*32768 + n0 + t8);
      float4 a0 = p0[0], a1 = p0[1];
      float4 b0 = p1[0], b1 = p1[1];
      const int rot = (swz + c) & 127;    // rotation keeps everything inside the row
      int di = t8*68 + (rot>>1);
      basep[di      ] = pk2(a0.x, b0.x);
      basep[di+  68 ] = pk2(a0.y, b0.y);
      basep[di+ 136 ] = pk2(a0.z, b0.z);
      basep[di+ 204 ] = pk2(a0.w, b0.w);
      basep[di+ 272 ] = pk2(a1.x, b1.x);
      basep[di+ 340 ] = pk2(a1.y, b1.y);
      basep[di+ 408 ] = pk2(a1.z, b1.z);
      basep[di+ 476 ] = pk2(a1.w, b1.w);
    }
  }
  __syncthreads();
  const int wave = tid >> 6, lane = tid & 63;
  const int wm = (wave & 1) << 6;   // oc half
  const int wn = (wave >> 1) << 6;  // token half
  const int lm = lane & 15, lq = lane >> 4;
  u16* outb = qkvvT + (size_t)b*512*32768;
  for(int s=0;s<4;++s){
    const int oc0 = s << 7;
    f32x4 acc[4][4] = {};
    const u16* Arow = Wqb + (oc0 + wm + lm)*128 + lq*8;
    #pragma unroll
    for(int ks=0; ks<4; ++ks){
      bf16x8 af[4], bfr[4];
      #pragma unroll
      for(int mt=0;mt<4;++mt) af[mt] = *(const bf16x8*)(Arow + mt*2048 + ks*32);
      #pragma unroll
      for(int nt=0;nt<4;++nt){
        const int tr = wn + nt*16 + lm;
        const int rot = ((((tr>>3)&3)<<3) + ks*32 + lq*8) & 127;
        bfr[nt] = *(const bf16x8*)(&lB[tr*K1PAD + rot]);
      }
      #pragma unroll
      for(int mt=0;mt<4;++mt)
        #pragma unroll
        for(int nt=0;nt<4;++nt)
          acc[mt][nt] = MFMA16(af[mt], bfr[nt], acc[mt][nt]);
    }
    #pragma unroll
    for(int mt=0;mt<4;++mt){
      const int ocr = oc0 + wm + mt*16 + lq*4;
      #pragma unroll
      for(int nt=0;nt<4;++nt){
        const int n = n0 + wn + nt*16 + lm;
        #pragma unroll
        for(int r=0;r<4;++r) outb[(size_t)(ocr+r)*32768 + n] = f2bf(acc[mt][nt][r]);
      }
    }
    if(s < 2){   // q (oc 0..127) and k (128..255) row sum-of-squares
      const int cbase = b*256 + oc0 + wm;
      #pragma unroll
      for(int mt=0;mt<4;++mt){
        #pragma unroll
        for(int r=0;r<4;++r){
          float ss = acc[mt][0][r]*acc[mt][0][r] + acc[mt][1][r]*acc[mt][1][r]
                   + acc[mt][2][r]*acc[mt][2][r] + acc[mt][3][r]*acc[mt][3][r];
          ss += __shfl_xor(ss, 1); ss += __shfl_xor(ss, 2);
          ss += __shfl_xor(ss, 4); ss += __shfl_xor(ss, 8);
          if(lm == 0) atomicAdd(&sumsq[cbase + mt*16 + lq*4 + r], ss);
        }
      }
    }
  }
}

// ============ K2: fold fc(1x1) into depthwise-grouped conv weights (fp32 in) ======
// W_eff layout: [g 32][j 16][k 27][ol 4] fp32 ; oc = g*4+ol
__global__ void k2_weff(const float* __restrict__ Wdep, const float* __restrict__ Wfc,
                        const float* __restrict__ bdep, const float* __restrict__ bfc,
                        float* __restrict__ W_eff, float* __restrict__ bias_eff){
  int idx = blockIdx.x*256 + threadIdx.x;
  if(idx < 55296){
    int ol = idx & 3;
    int k  = (idx >> 2) % 27;
    int j  = (idx / 108) & 15;
    int g  = idx / 1728;
    int oc = g*4 + ol;
    float s = 0.f;
    for(int o=0;o<16;++o) s += Wdep[(oc*16 + o)*27 + k] * Wfc[o*16 + j];
    W_eff[idx] = s;
  }
  if(idx < 128){
    float s = bdep[idx];
    for(int o=0;o<16;++o){
      float wsum = 0.f;
      for(int k=0;k<27;++k) wsum += Wdep[(idx*16 + o)*27 + k];
      s += wsum * bfc[o];  // b_fc == 0 in this problem (boundary fold vacuous)
    }
    bias_eff[idx] = s;
  }
}

// ============ K2c: invn = rsqrt of fused sumsq (replaces k2b's full re-read) ====
__global__ __launch_bounds__(256) void k2c_invn(const float* __restrict__ sumsq, float* __restrict__ invn){
  int i = blockIdx.x*256 + threadIdx.x;
  invn[i] = 1.0f / fmaxf(sqrtf(sumsq[i]), 1e-12f);
}

// ============ K3: k_proj / v_SA_proj = rows @ W_E^T  (MFMA, K split, atomics) ====
__global__ __launch_bounds__(256) void k3_proj(const u16* __restrict__ qkvvT, const u16* __restrict__ WEb,
                                               float* __restrict__ kp, float* __restrict__ vp){
  const int kc = blockIdx.x;            // K chunk of 1024
  const int b  = blockIdx.y;
  const int ts = blockIdx.z >> 1;       // 0: k, 1: v_SA
  const int rh = (blockIdx.z & 1) << 6; // row half
  const int wave = threadIdx.x >> 6, lane = threadIdx.x & 63;
  const int lm = lane & 15, lq = lane >> 4;
  const int coff = ts ? 384 : 128;
  const u16* Arow = qkvvT + ((size_t)b*512 + coff + rh + wave*16 + lm)*32768 + kc*1024 + lq*8;
  f32x4 acc[4] = {};
  for(int ks=0; ks<32; ++ks){
    bf16x8 af = *(const bf16x8*)(Arow + ks*32);
    #pragma unroll
    for(int nt=0;nt<4;++nt){
      bf16x8 bfr = *(const bf16x8*)(WEb + (size_t)(nt*16 + lm)*32768 + kc*1024 + ks*32 + lq*8);
      acc[nt] = MFMA16(af, bfr, acc[nt]);
    }
  }
  float* out = (ts ? vp : kp) + (size_t)b*128*64;
  const int r0 = rh + wave*16 + lq*4;
  #pragma unroll
  for(int nt=0;nt<4;++nt){
    const int p = nt*16 + lm;
    #pragma unroll
    for(int r=0;r<4;++r) atomicAdd(&out[(r0+r)*64 + p], acc[nt][r]);
  }
}

// ============ K4: Gram G[b,h][d][e] = sum_n q[d,n]k[e,n] (MFMA, K split) =========
__global__ __launch_bounds__(64) void k4_gram(const u16* __restrict__ qkvvT, float* __restrict__ G){
  const int kc = blockIdx.x, b = blockIdx.y, h = blockIdx.z;
  const int lane = threadIdx.x, lm = lane & 15, lq = lane >> 4;
  const u16* qb = qkvvT + ((size_t)b*512 + h*32)*32768 + kc*512 + lq*8;
  const u16* kb = qb + (size_t)128*32768;
  f32x4 acc[2][2] = {};
  for(int ks=0; ks<16; ++ks){
    bf16x8 af[2], bfr[2];
    af[0]  = *(const bf16x8*)(qb + (size_t)lm*32768 + ks*32);
    af[1]  = *(const bf16x8*)(qb + (size_t)(16+lm)*32768 + ks*32);
    bfr[0] = *(const bf16x8*)(kb + (size_t)lm*32768 + ks*32);
    bfr[1] = *(const bf16x8*)(kb + (size_t)(16+lm)*32768 + ks*32);
    #pragma unroll
    for(int mt=0;mt<2;++mt)
      #pragma unroll
      for(int nt=0;nt<2;++nt) acc[mt][nt] = MFMA16(af[mt], bfr[nt], acc[mt][nt]);
  }
  float* Gb = G + (size_t)(b*4 + h)*1024;
  #pragma unroll
  for(int mt=0;mt<2;++mt)
    #pragma unroll
    for(int nt=0;nt<2;++nt)
      #pragma unroll
      for(int r=0;r<4;++r){
        int d = mt*16 + lq*4 + r, e = nt*16 + lm;
        atomicAdd(&Gb[d*32 + e], acc[mt][nt][r]);
      }
}

// ============ K4b: scale+softmax(attn_CA) then M2 = W_out2 * attn_CA =============
__global__ __launch_bounds__(256) void k4b_softmax_m2(const float* __restrict__ G, const float* __restrict__ invn,
                                                      const float* __restrict__ temp, const float* __restrict__ Wout2,
                                                      u16* __restrict__ M2){
  const int b = blockIdx.x >> 2, h = blockIdx.x & 3;
  __shared__ float A[32][33];
  const float* Gb = G + (size_t)(b*4 + h)*1024;
  const float* inb = invn + b*256;
  const float th = temp[h];
  const int tid = threadIdx.x;
  if(tid < 32){
    const int d = tid;
    const float iq = inb[h*32 + d];
    float row[32]; float mx = -1e30f;
    #pragma unroll
    for(int e=0;e<32;++e){
      float v = Gb[d*32+e] * iq * inb[128 + h*32 + e] * th;
      row[e] = v; mx = fmaxf(mx, v);
    }
    float s = 0.f;
    #pragma unroll
    for(int e=0;e<32;++e){ float ee = __expf(row[e]-mx); row[e] = ee; s += ee; }
    const float rs = 1.0f/s;
    #pragma unroll
    for(int e=0;e<32;++e) A[d][e] = row[e]*rs;
  }
  __syncthreads();
  for(int o = tid; o < 2048; o += 256){
    const int j = o >> 5, e = o & 31;
    float s = 0.f;
    #pragma unroll
    for(int d=0;d<32;++d) s += Wout2[j*128 + h*32 + d] * A[d][e];
    M2[((size_t)b*64 + j)*128 + h*32 + e] = f2bf(s);
  }
}

// ============ K5 v2: spatial (Linformer) attention, scalar-path weights ==========
// kp/vp/bE/invn rows are wave-uniform -> uniform float4 loads (s_load_dwordx4,
// SMEM pipe) instead of LDS broadcast ds_reads (old version: ~1024 ds_read_b128
// per wave = LDS-issue-bound). bE folded algebraically: s_p = dot + qsum*bE_p;
// out_d = r*(dot_d + pb), pb = sum_p P_p*bE_p. No LDS at all.
__global__ __launch_bounds__(256) void k5_xsa(const u16* __restrict__ qkvvT, const float* __restrict__ kp,
                                              const float* __restrict__ vp, const float* __restrict__ invn,
                                              const float* __restrict__ bE, const float* __restrict__ temp2,
                                              u16* __restrict__ xsa){
  const int b = blockIdx.z, h = blockIdx.y, n0 = blockIdx.x*256;
  const int tid = threadIdx.x;
  const int n = n0 + tid;
  const u16* qb = qkvvT + ((size_t)b*512 + h*32)*32768 + n;
  const float* iqp = invn + b*256 + h*32;               // uniform
  const float* kpb = kp + ((size_t)b*128 + h*32)*64;    // row d at +d*64
  const float* vpb = vp + ((size_t)b*128 + h*32)*64;
  const float t2 = temp2[h];
  float s[64];
  #pragma unroll
  for(int p=0;p<64;++p) s[p]=0.f;
  float qsum = 0.f;
  for(int d=0; d<32; ++d){
    const float qv = bf2f(qb[(size_t)d*32768]) * iqp[d];
    qsum += qv;
    const float4* row = (const float4*)(kpb + d*64);    // uniform -> s_load
    #pragma unroll
    for(int p4=0;p4<16;++p4){
      float4 w = row[p4];
      s[p4*4+0] += qv*w.x; s[p4*4+1] += qv*w.y;
      s[p4*4+2] += qv*w.z; s[p4*4+3] += qv*w.w;
    }
  }
  const float4* be4 = (const float4*)bE;
  float mx = -1e30f;
  #pragma unroll
  for(int p4=0;p4<16;++p4){
    float4 be = be4[p4];
    float v0 = (s[p4*4+0] + qsum*be.x)*t2;
    float v1 = (s[p4*4+1] + qsum*be.y)*t2;
    float v2 = (s[p4*4+2] + qsum*be.z)*t2;
    float v3 = (s[p4*4+3] + qsum*be.w)*t2;
    s[p4*4+0]=v0; s[p4*4+1]=v1; s[p4*4+2]=v2; s[p4*4+3]=v3;
    mx = fmaxf(mx, fmaxf(fmaxf(v0,v1), fmaxf(v2,v3)));
  }
  float sum = 0.f;
  #pragma unroll
  for(int p=0;p<64;++p){ s[p] = __expf(s[p]-mx); sum += s[p]; }
  const float r = 1.0f/sum;
  float pb = 0.f;
  #pragma unroll
  for(int p4=0;p4<16;++p4){
    float4 be = be4[p4];
    pb += s[p4*4+0]*be.x + s[p4*4+1]*be.y + s[p4*4+2]*be.z + s[p4*4+3]*be.w;
  }
  u16* ob = xsa + (((size_t)b*4 + h)*32)*32768 + n;
  for(int d=0; d<32; ++d){
    const float4* row = (const float4*)(vpb + d*64);    // uniform -> s_load
    float acc = pb;
    #pragma unroll
    for(int p4=0;p4<16;++p4){
      float4 w = row[p4];
      acc += s[p4*4+0]*w.x + s[p4*4+1]*w.y + s[p4*4+2]*w.z + s[p4*4+3]*w.w;
    }
    ob[(size_t)d*32768] = f2bf(acc*r);
  }
}

// ============ K_conv v6: fused grouped 3x3x3 conv, z-tile 8 =====================
// FROZEN this round. r3 post-mortem: duration invariant under occupancy 31->47%
// => per-CU-pipe saturated (VALU issue ~66% eff ceiling + LDS pipe), not
// latency-bound. Scalar-FP32 structural floor ~140-180 us; next lever would be
// MFMA-ification (deferred).
#define CSX 36
#define CSZ 360            // 10*CSX
__global__ __launch_bounds__(256,6) void kconv(const u16* __restrict__ qkvvT, const float* __restrict__ W_eff,
                                               const float* __restrict__ bias_eff, u16* __restrict__ convo){
  __shared__ float lf[10*CSZ];   // 14,400 B
  const int zt = blockIdx.x >> 2, yt = blockIdx.x & 3;
  const int g = blockIdx.y, b = blockIdx.z;
  const int tid = threadIdx.x;
  const int z0 = zt << 3, y0 = yt << 3;
  const int lz = tid >> 5;                // output z (0..7)
  const int vy = (tid >> 2) & 7;
  const int x0 = (tid & 3) << 3;
  float acc[4][8];
  #pragma unroll
  for(int oc=0;oc<4;++oc)
    #pragma unroll
    for(int xi=0;xi<8;++xi) acc[oc][xi] = 0.f;
  const u16* qb = qkvvT + (size_t)b*512*32768;
  // staging: threads 0..99 each own one (z-row, y-row)
  const int sz = tid / 10, sy = tid - sz*10;
  const int gz = z0 + sz - 1, gy = y0 + sy - 1;
  const bool srow_ok = (tid < 100) && ((unsigned)gz < 32u) && ((unsigned)gy < 32u);
  float2* d2 = (float2*)&lf[sz*CSZ + sy*CSX];
  const float* Wgbase = W_eff + (size_t)(g*16)*108;

  for(int p=0;p<16;++p){
    __syncthreads();   // previous pass compute done
    if(tid < 100){
      if(srow_ok){
        const u16* src = qb + ((size_t)(p*32 + g))*32768 + gz*1024 + gy*32;
        float carry = 0.f;
        #pragma unroll
        for(int q=0;q<4;++q){
          bf16x8 v = *(const bf16x8*)(src + q*8);
          float w0=bf2f((u16)v[0]), w1=bf2f((u16)v[1]), w2=bf2f((u16)v[2]), w3=bf2f((u16)v[3]);
          float w4=bf2f((u16)v[4]), w5=bf2f((u16)v[5]), w6=bf2f((u16)v[6]), w7=bf2f((u16)v[7]);
          d2[q*4+0] = make_float2(carry, w0);
          d2[q*4+1] = make_float2(w1, w2);
          d2[q*4+2] = make_float2(w3, w4);
          d2[q*4+3] = make_float2(w5, w6);
          carry = w7;
        }
        d2[16] = make_float2(carry, 0.f);
      } else {
        #pragma unroll
        for(int i=0;i<17;++i) d2[i] = make_float2(0.f, 0.f);
      }
    }
    __syncthreads();
    const float* Wg = Wgbase + p*108;    // [kz3][ky3][kx3][oc4], wave-uniform
    #pragma unroll
    for(int dy=0;dy<3;++dy){
      #pragma unroll
      for(int dz=0;dz<3;++dz){
        const float* row = &lf[(lz+dz)*CSZ + (vy+dy)*CSX + x0];
        float4 fa = *(const float4*)(row);
        float4 fb = *(const float4*)(row+4);
        float2 fc = *(const float2*)(row+8);
        float fw[10] = {fa.x,fa.y,fa.z,fa.w, fb.x,fb.y,fb.z,fb.w, fc.x,fc.y};
        const float* Wb = Wg + (dz*3+dy)*12;
        #pragma unroll
        for(int kx=0;kx<3;++kx){
          float4 wv = *(const float4*)(Wb + kx*4);
          #pragma unroll
          for(int xi=0;xi<8;++xi){
            float f = fw[xi+kx];
            acc[0][xi] += wv.x*f; acc[1][xi] += wv.y*f;
            acc[2][xi] += wv.z*f; acc[3][xi] += wv.w*f;
          }
        }
      }
    }
  }
  const float4 bi = *(const float4*)(bias_eff + g*4);  // wave-uniform -> s_load
  const int nb = (z0 + lz)*1024 + (y0+vy)*32 + x0;
  u16* ob = convo + ((size_t)b*32768 + nb)*128 + g*4;
  #pragma unroll
  for(int xi=0;xi<8;++xi){
    unsigned long long pk = (unsigned long long)f2bf(acc[0][xi] + bi.x)
                          | ((unsigned long long)f2bf(acc[1][xi] + bi.y) << 16)
                          | ((unsigned long long)f2bf(acc[2][xi] + bi.z) << 32)
                          | ((unsigned long long)f2bf(acc[3][xi] + bi.w) << 48);
    *(unsigned long long*)(ob + (size_t)xi*128) = pk;
  }
}

// ============ K6: output assembly (SA gather-GEMM + CA GEMM + conv + rates), fp32 out
#define K6PAD 136
__global__ __launch_bounds__(256) void k6_out(const u16* __restrict__ qkvvT, const u16* __restrict__ xsa,
                                              const u16* __restrict__ conv, const u16* __restrict__ M2,
                                              const u16* __restrict__ Woutb, const float* __restrict__ bout,
                                              const float* __restrict__ bout2, const float* __restrict__ rate,
                                              const float* __restrict__ rate2, float* __restrict__ out){
  __shared__ u16 lA[128*K6PAD];
  const int tile = blockIdx.x;
  const int b  = tile >> 8;
  const int n0 = (tile & 255) << 7;
  const int tid = threadIdx.x;
  const int hh = (n0 >> 8) & 3;   // constant per 128-token tile
  const int dh = n0 >> 10;
  // ---- phase A: stage scrambled x_SA segment (contiguous!) -> lA[tok][c']
  const u16* xseg = xsa + (((size_t)b*4 + hh)*32 + dh)*32768 + ((size_t)(n0 & 255) << 7);
  {
    const int r = tid >> 1, off = (tid & 1) << 6;
    const u16* src = xseg + r*128 + off;
    u16* dst = &lA[r*K6PAD + off];
    #pragma unroll
    for(int q=0;q<8;++q) *(bf16x8*)(dst + q*8) = *(const bf16x8*)(src + q*8);
  }
  __syncthreads();
  const int wave = tid >> 6, lane = tid & 63;
  const int lm = lane & 15, lq = lane >> 4;
  f32x4 accS[2][4] = {};
  #pragma unroll
  for(int ks=0;ks<4;++ks){
    bf16x8 a0 = *(const bf16x8*)(&lA[(wave*32 + lm)*K6PAD + ks*32 + lq*8]);
    bf16x8 a1 = *(const bf16x8*)(&lA[(wave*32 + 16 + lm)*K6PAD + ks*32 + lq*8]);
    #pragma unroll
    for(int nt=0;nt<4;++nt){
      bf16x8 bw = *(const bf16x8*)(Woutb + (nt*16 + lm)*128 + ks*32 + lq*8);
      accS[0][nt] = MFMA16(a0, bw, accS[0][nt]);
      accS[1][nt] = MFMA16(a1, bw, accS[1][nt]);
    }
  }
  __syncthreads();
  // ---- phase B: stage v_CA tile transposed -> lA[tok][c'']
  {
    const int cb = tid >> 4, t8 = (tid & 15) << 3;
    const u16* vb = qkvvT + ((size_t)b*512 + 256)*32768 + n0;
    #pragma unroll
    for(int r2=0;r2<8;++r2){
      int c = cb + (r2<<4);
      bf16x8 v = *(const bf16x8*)(vb + (size_t)c*32768 + t8);
      #pragma unroll
      for(int j=0;j<8;++j) lA[(t8+j)*K6PAD + c] = (u16)v[j];
    }
  }
  __syncthreads();
  f32x4 accC[2][4] = {};
  #pragma unroll
  for(int ks=0;ks<4;++ks){
    bf16x8 a0 = *(const bf16x8*)(&lA[(wave*32 + lm)*K6PAD + ks*32 + lq*8]);
    bf16x8 a1 = *(const bf16x8*)(&lA[(wave*32 + 16 + lm)*K6PAD + ks*32 + lq*8]);
    #pragma unroll
    for(int nt=0;nt<4;++nt){
      bf16x8 bm = *(const bf16x8*)(M2 + ((size_t)b*64 + nt*16 + lm)*128 + ks*32 + lq*8);
      accC[0][nt] = MFMA16(a0, bm, accC[0][nt]);
      accC[1][nt] = MFMA16(a1, bm, accC[1][nt]);
    }
  }
  const float rt = rate[0], rt2 = rate2[0];
  float* ob = out + ((size_t)b*32768 + n0)*128;
  const u16* cbp = conv + ((size_t)b*32768 + n0)*128;
  #pragma unroll
  for(int mt=0;mt<2;++mt){
    #pragma unroll
    for(int r=0;r<4;++r){
      const int tok = wave*32 + mt*16 + lq*4 + r;
      #pragma unroll
      for(int nt=0;nt<4;++nt){
        const int j = nt*16 + lm;
        float sa = accS[mt][nt][r] + bout[j];
        float ca = accC[mt][nt][r] + bout2[j];
        float c1 = bf2f(cbp[(size_t)tok*128 + j]);
        float c2 = bf2f(cbp[(size_t)tok*128 + 64 + j]);
        ob[(size_t)tok*128 + j]      = rt*sa + rt2*c1;
        ob[(size_t)tok*128 + 64 + j] = rt*ca + rt2*c2;
      }
    }
  }
}

extern "C" void kernel_launch(void* const* d_in, const int* in_sizes, int n_in,
                              void* d_out, int out_size, void* d_ws, size_t ws_size,
                              hipStream_t stream){
  const float* x     = (const float*)d_in[0];
  const float* Wq    = (const float*)d_in[1];
  const float* Wfc   = (const float*)d_in[2];
  const float* bfc   = (const float*)d_in[3];
  const float* Wdep  = (const float*)d_in[4];
  const float* bdep  = (const float*)d_in[5];
  const float* WE    = (const float*)d_in[6];
  const float* bE    = (const float*)d_in[7];
  const float* temp  = (const float*)d_in[8];
  const float* temp2 = (const float*)d_in[9];
  const float* rate  = (const float*)d_in[10];
  const float* rate2 = (const float*)d_in[11];
  const float* Wout  = (const float*)d_in[12];
  const float* bout  = (const float*)d_in[13];
  const float* Wout2 = (const float*)d_in[14];
  const float* bout2 = (const float*)d_in[15];
  float* outp = (float*)d_out;

  char* w = (char*)d_ws;
  size_t off = 0;
  auto alloc = [&](size_t bytes)->char*{ char* p = w + off; off += (bytes + 255) & ~(size_t)255; return p; };
  u16*   qkvvT  = (u16*)  alloc((size_t)4*512*32768*2);   // 134 MB, channel-major
  u16*   xsa    = (u16*)  alloc((size_t)4*4*32*32768*2);  // 33.5 MB
  u16*   convb  = (u16*)  alloc((size_t)4*32768*128*2);   // 33.5 MB, token-major
  float* W_eff  = (float*)alloc(55296*4);
  float* biasef = (float*)alloc(128*4);
  float* invn   = (float*)alloc(1024*4);
  float* kp     = (float*)alloc(32768*4);
  float* vp     = (float*)alloc(32768*4);
  float* G      = (float*)alloc(16384*4);
  float* sumsq  = (float*)alloc(1024*4);
  u16*   M2     = (u16*)  alloc(32768*2);
  u16*   WEb    = (u16*)  alloc((size_t)2097152*2);       // bf16 copies of MFMA weights
  u16*   Wqb    = (u16*)  alloc(65536*2);
  u16*   Woutb  = (u16*)  alloc(8192*2);

  // zero the fp32 atomic-accumulation buffers (kp|vp|G|sumsq are contiguous)
  hipMemsetAsync(kp, 0, (size_t)(32768+32768+16384+1024)*4, stream);

  kcvt3         <<<2120,          256, 0, stream>>>(WE, WEb, Wq, Wqb, Wout, Woutb);
  k1_qkvv       <<<1024,          256, 0, stream>>>(x, Wqb, qkvvT, sumsq);
  k2c_invn      <<<4,             256, 0, stream>>>(sumsq, invn);
  k2_weff       <<<216,           256, 0, stream>>>(Wdep, Wfc, bdep, bfc, W_eff, biasef);
  k3_proj       <<<dim3(32,4,4),  256, 0, stream>>>(qkvvT, WEb, kp, vp);
  k4_gram       <<<dim3(64,4,4),   64, 0, stream>>>(qkvvT, G);
  k4b_softmax_m2<<<16,            256, 0, stream>>>(G, invn, temp, Wout2, M2);
  k5_xsa        <<<dim3(128,4,4), 256, 0, stream>>>(qkvvT, kp, vp, invn, bE, temp2, xsa);
  kconv         <<<dim3(16,32,4), 256, 0, stream>>>(qkvvT, W_eff, biasef, convb);
  k6_out        <<<1024,          256, 0, stream>>>(qkvvT, xsa, convb, M2, Woutb, bout, bout2, rate, rate2, outp);
}

// Round 5
// 556.270 us; speedup vs baseline: 1.2946x; 1.2946x over previous
//
#include <hip/hip_runtime.h>
#include <hip/hip_bf16.h>

typedef unsigned short u16;
typedef __attribute__((ext_vector_type(8))) short bf16x8;
typedef __attribute__((ext_vector_type(4))) float f32x4;

#define MFMA16(a,b,c) __builtin_amdgcn_mfma_f32_16x16x32_bf16((a),(b),(c),0,0,0)

__device__ __forceinline__ float bf2f(u16 u){ union{unsigned int i; float f;} v; v.i=((unsigned int)u)<<16; return v.f; }
__device__ __forceinline__ u16 f2bf(float f){ union{float f; unsigned int i;} v; v.f=f; unsigned int r=v.i+0x7fffu+((v.i>>16)&1u); return (u16)(r>>16); }
__device__ __forceinline__ unsigned int pk2(float a, float b){
  __hip_bfloat162 h = __float22bfloat162_rn(make_float2(a,b));
  union{ __hip_bfloat162 h; unsigned int u; } v; v.h = h; return v.u;
}

// ============ K0: fp32 -> bf16 conversions for the 3 MFMA weights, one launch ====
__global__ __launch_bounds__(256) void kcvt3(const float* __restrict__ WE, u16* __restrict__ WEb,
                                             const float* __restrict__ Wq, u16* __restrict__ Wqb,
                                             const float* __restrict__ Wo, u16* __restrict__ Wob){
  int bid = blockIdx.x;
  const float* src; u16* dst; int base;
  if(bid < 2048){ src = WE; dst = WEb; base = bid*1024; }
  else if(bid < 2112){ src = Wq; dst = Wqb; base = (bid-2048)*1024; }
  else { src = Wo; dst = Wob; base = (bid-2112)*1024; }
  int i = base + threadIdx.x*4;
  float4 v = *(const float4*)(src + i);
  ushort4 o; o.x = f2bf(v.x); o.y = f2bf(v.y); o.z = f2bf(v.z); o.w = f2bf(v.w);
  *(ushort4*)(dst + i) = o;
}

// ================= K1: qkvvT[b][oc][n] = sum_c Wq[oc][c]*x[b][c][n] (MFMA) =========
#define K1PAD 136
__global__ __launch_bounds__(256) void k1_qkvv(const float* __restrict__ x, const u16* __restrict__ Wqb, u16* __restrict__ qkvvT){
  __shared__ u16 lB[128*K1PAD];
  const int tile = blockIdx.x;            // b*256 + token tile
  const int b  = tile >> 8;
  const int n0 = (tile & 255) << 7;
  const int tid = threadIdx.x;
  const float* xb = x + (size_t)b*128*32768;
  {
    const int cb = (tid >> 4) << 1;       // even channel 0..30
    const int m  = tid & 15;
    const int t8 = m << 3;                // 8-token block
    const int swz = (m & 3) << 3;         // rotation amount (u16 units)
    unsigned int* basep = (unsigned int*)lB;
    #pragma unroll
    for(int r=0;r<4;++r){
      const int c = cb + (r<<5);
      const float4* p0 = (const float4*)(xb + (size_t)c*32768 + n0 + t8);
      const float4* p1 = (const float4*)(xb + (size_t)(c+1)*32768 + n0 + t8);
      float4 a0 = p0[0], a1 = p0[1];
      float4 b0 = p1[0], b1 = p1[1];
      const int rot = (swz + c) & 127;    // rotation keeps everything inside the row
      int di = t8*68 + (rot>>1);
      basep[di      ] = pk2(a0.x, b0.x);
      basep[di+  68 ] = pk2(a0.y, b0.y);
      basep[di+ 136 ] = pk2(a0.z, b0.z);
      basep[di+ 204 ] = pk2(a0.w, b0.w);
      basep[di+ 272 ] = pk2(a1.x, b1.x);
      basep[di+ 340 ] = pk2(a1.y, b1.y);
      basep[di+ 408 ] = pk2(a1.z, b1.z);
      basep[di+ 476 ] = pk2(a1.w, b1.w);
    }
  }
  __syncthreads();
  const int wave = tid >> 6, lane = tid & 63;
  const int wm = (wave & 1) << 6;   // oc half
  const int wn = (wave >> 1) << 6;  // token half
  const int lm = lane & 15, lq = lane >> 4;
  u16* outb = qkvvT + (size_t)b*512*32768;
  for(int s=0;s<4;++s){
    const int oc0 = s << 7;
    f32x4 acc[4][4] = {};
    const u16* Arow = Wqb + (oc0 + wm + lm)*128 + lq*8;
    #pragma unroll
    for(int ks=0; ks<4; ++ks){
      bf16x8 af[4], bfr[4];
      #pragma unroll
      for(int mt=0;mt<4;++mt) af[mt] = *(const bf16x8*)(Arow + mt*2048 + ks*32);
      #pragma unroll
      for(int nt=0;nt<4;++nt){
        const int tr = wn + nt*16 + lm;
        const int rot = ((((tr>>3)&3)<<3) + ks*32 + lq*8) & 127;
        bfr[nt] = *(const bf16x8*)(&lB[tr*K1PAD + rot]);
      }
      #pragma unroll
      for(int mt=0;mt<4;++mt)
        #pragma unroll
        for(int nt=0;nt<4;++nt)
          acc[mt][nt] = MFMA16(af[mt], bfr[nt], acc[mt][nt]);
    }
    #pragma unroll
    for(int mt=0;mt<4;++mt){
      const int ocr = oc0 + wm + mt*16 + lq*4;
      #pragma unroll
      for(int nt=0;nt<4;++nt){
        const int n = n0 + wn + nt*16 + lm;
        #pragma unroll
        for(int r=0;r<4;++r) outb[(size_t)(ocr+r)*32768 + n] = f2bf(acc[mt][nt][r]);
      }
    }
  }
}

// ============ K2: fold fc(1x1) into depthwise-grouped conv weights (fp32 in) ======
// W_eff layout: [g 32][j 16][k 27][ol 4] fp32 ; oc = g*4+ol
__global__ void k2_weff(const float* __restrict__ Wdep, const float* __restrict__ Wfc,
                        const float* __restrict__ bdep, const float* __restrict__ bfc,
                        float* __restrict__ W_eff, float* __restrict__ bias_eff){
  int idx = blockIdx.x*256 + threadIdx.x;
  if(idx < 55296){
    int ol = idx & 3;
    int k  = (idx >> 2) % 27;
    int j  = (idx / 108) & 15;
    int g  = idx / 1728;
    int oc = g*4 + ol;
    float s = 0.f;
    for(int o=0;o<16;++o) s += Wdep[(oc*16 + o)*27 + k] * Wfc[o*16 + j];
    W_eff[idx] = s;
  }
  if(idx < 128){
    float s = bdep[idx];
    for(int o=0;o<16;++o){
      float wsum = 0.f;
      for(int k=0;k<27;++k) wsum += Wdep[(idx*16 + o)*27 + k];
      s += wsum * bfc[o];  // b_fc == 0 in this problem (boundary fold vacuous)
    }
    bias_eff[idx] = s;
  }
}

// ============ K2b: inverse l2 norms of q rows (c<128) and k rows (c 128..255) ====
__global__ __launch_bounds__(256) void k2b_norms(const u16* __restrict__ qkvvT, float* __restrict__ invn){
  const int b = blockIdx.x >> 8, c = blockIdx.x & 255;
  const u16* row = qkvvT + ((size_t)b*512 + c)*32768;
  float s = 0.f;
  for(int n = threadIdx.x*8; n < 32768; n += 2048){
    bf16x8 v = *(const bf16x8*)(row + n);
    #pragma unroll
    for(int j=0;j<8;++j){ float f = bf2f((u16)v[j]); s += f*f; }
  }
  for(int off=32; off; off>>=1) s += __shfl_down(s, off, 64);
  __shared__ float wsum[4];
  if((threadIdx.x & 63)==0) wsum[threadIdx.x>>6] = s;
  __syncthreads();
  if(threadIdx.x==0){
    float t = wsum[0]+wsum[1]+wsum[2]+wsum[3];
    invn[blockIdx.x] = 1.0f / fmaxf(sqrtf(t), 1e-12f);
  }
}

// ============ K3: k_proj / v_SA_proj = rows @ W_E^T  (MFMA, K split, atomics) ====
__global__ __launch_bounds__(256) void k3_proj(const u16* __restrict__ qkvvT, const u16* __restrict__ WEb,
                                               float* __restrict__ kp, float* __restrict__ vp){
  const int kc = blockIdx.x;            // K chunk of 1024
  const int b  = blockIdx.y;
  const int ts = blockIdx.z >> 1;       // 0: k, 1: v_SA
  const int rh = (blockIdx.z & 1) << 6; // row half
  const int wave = threadIdx.x >> 6, lane = threadIdx.x & 63;
  const int lm = lane & 15, lq = lane >> 4;
  const int coff = ts ? 384 : 128;
  const u16* Arow = qkvvT + ((size_t)b*512 + coff + rh + wave*16 + lm)*32768 + kc*1024 + lq*8;
  f32x4 acc[4] = {};
  for(int ks=0; ks<32; ++ks){
    bf16x8 af = *(const bf16x8*)(Arow + ks*32);
    #pragma unroll
    for(int nt=0;nt<4;++nt){
      bf16x8 bfr = *(const bf16x8*)(WEb + (size_t)(nt*16 + lm)*32768 + kc*1024 + ks*32 + lq*8);
      acc[nt] = MFMA16(af, bfr, acc[nt]);
    }
  }
  float* out = (ts ? vp : kp) + (size_t)b*128*64;
  const int r0 = rh + wave*16 + lq*4;
  #pragma unroll
  for(int nt=0;nt<4;++nt){
    const int p = nt*16 + lm;
    #pragma unroll
    for(int r=0;r<4;++r) atomicAdd(&out[(r0+r)*64 + p], acc[nt][r]);
  }
}

// ============ K4: Gram G[b,h][d][e] = sum_n q[d,n]k[e,n] (MFMA, K split) =========
__global__ __launch_bounds__(64) void k4_gram(const u16* __restrict__ qkvvT, float* __restrict__ G){
  const int kc = blockIdx.x, b = blockIdx.y, h = blockIdx.z;
  const int lane = threadIdx.x, lm = lane & 15, lq = lane >> 4;
  const u16* qb = qkvvT + ((size_t)b*512 + h*32)*32768 + kc*512 + lq*8;
  const u16* kb = qb + (size_t)128*32768;
  f32x4 acc[2][2] = {};
  for(int ks=0; ks<16; ++ks){
    bf16x8 af[2], bfr[2];
    af[0]  = *(const bf16x8*)(qb + (size_t)lm*32768 + ks*32);
    af[1]  = *(const bf16x8*)(qb + (size_t)(16+lm)*32768 + ks*32);
    bfr[0] = *(const bf16x8*)(kb + (size_t)lm*32768 + ks*32);
    bfr[1] = *(const bf16x8*)(kb + (size_t)(16+lm)*32768 + ks*32);
    #pragma unroll
    for(int mt=0;mt<2;++mt)
      #pragma unroll
      for(int nt=0;nt<2;++nt) acc[mt][nt] = MFMA16(af[mt], bfr[nt], acc[mt][nt]);
  }
  float* Gb = G + (size_t)(b*4 + h)*1024;
  #pragma unroll
  for(int mt=0;mt<2;++mt)
    #pragma unroll
    for(int nt=0;nt<2;++nt)
      #pragma unroll
      for(int r=0;r<4;++r){
        int d = mt*16 + lq*4 + r, e = nt*16 + lm;
        atomicAdd(&Gb[d*32 + e], acc[mt][nt][r]);
      }
}

// ============ K4b: scale+softmax(attn_CA) then M2 = W_out2 * attn_CA =============
__global__ __launch_bounds__(256) void k4b_softmax_m2(const float* __restrict__ G, const float* __restrict__ invn,
                                                      const float* __restrict__ temp, const float* __restrict__ Wout2,
                                                      u16* __restrict__ M2){
  const int b = blockIdx.x >> 2, h = blockIdx.x & 3;
  __shared__ float A[32][33];
  const float* Gb = G + (size_t)(b*4 + h)*1024;
  const float* inb = invn + b*256;
  const float th = temp[h];
  const int tid = threadIdx.x;
  if(tid < 32){
    const int d = tid;
    const float iq = inb[h*32 + d];
    float row[32]; float mx = -1e30f;
    #pragma unroll
    for(int e=0;e<32;++e){
      float v = Gb[d*32+e] * iq * inb[128 + h*32 + e] * th;
      row[e] = v; mx = fmaxf(mx, v);
    }
    float s = 0.f;
    #pragma unroll
    for(int e=0;e<32;++e){ float ee = __expf(row[e]-mx); row[e] = ee; s += ee; }
    const float rs = 1.0f/s;
    #pragma unroll
    for(int e=0;e<32;++e) A[d][e] = row[e]*rs;
  }
  __syncthreads();
  for(int o = tid; o < 2048; o += 256){
    const int j = o >> 5, e = o & 31;
    float s = 0.f;
    #pragma unroll
    for(int d=0;d<32;++d) s += Wout2[j*128 + h*32 + d] * A[d][e];
    M2[((size_t)b*64 + j)*128 + h*32 + e] = f2bf(s);
  }
}

// ============ K5 v3: Linformer attention via MFMA ================================
// S^T = mfma(A = (kp+bE) [p][d] hi/lo bf16, B = qn hi/lo) : M=p64, N=tok, K=d32.
// Softmax in-register: token's 64 p live in 4 lanes (lm, lq=0..3) x 16 regs ->
// 2x shfl_xor(16,32). P (single bf16; error attenuated ~0.23x by W_out) bounced
// through per-wave LDS to B layout. out^T = mfma(A = (vp+bE) hi/lo, B = P);
// 1/sum folded post-PV. Replaces ~5120 scalar-VALU instr/wave with ~500 + 20 MFMA.
// v2 lesson: broadcast operands must NOT go via s_load (SMEM/DS lgkmcnt is
// out-of-order -> per-iteration lgkmcnt(0) serialization).
__global__ __launch_bounds__(256) void k5_xsa(const u16* __restrict__ qkvvT, const float* __restrict__ kp,
                                              const float* __restrict__ vp, const float* __restrict__ invn,
                                              const float* __restrict__ bE, const float* __restrict__ temp2,
                                              u16* __restrict__ xsa){
  __shared__ __align__(16) u16 L[14336];
  __shared__ float liqt[32];
  u16* lkAh = L;            // [64][40] : kp^T + bE, hi
  u16* lkAl = L + 2560;     // lo
  u16* lvAh = L + 5120;     // [32][72] : vp + bE, hi
  u16* lvAl = L + 7424;     // lo
  u16* Pl   = L + 9728;     // [4 waves][16][72] per-wave P bounce
  const int b = blockIdx.z, h = blockIdx.y;
  const int tid = threadIdx.x;
  const float t2 = temp2[h];
  {  // stage lkA = kp^T + bE (hi/lo)
    const int p = tid >> 2, d8 = (tid & 3) << 3;
    const float be = bE[p];
    const float* kpb = kp + ((size_t)b*128 + h*32)*64;
    #pragma unroll
    for(int j=0;j<8;++j){
      float v = kpb[(size_t)(d8+j)*64 + p] + be;
      u16 hi = f2bf(v);
      lkAh[p*40 + d8 + j] = hi;
      lkAl[p*40 + d8 + j] = f2bf(v - bf2f(hi));
    }
  }
  {  // stage lvA = vp + bE (hi/lo)
    const int d = tid >> 3, p8 = (tid & 7) << 3;
    const float* vpb = vp + ((size_t)b*128 + h*32)*64;
    #pragma unroll
    for(int j=0;j<8;++j){
      float v = vpb[(size_t)d*64 + p8 + j] + bE[p8+j];
      u16 hi = f2bf(v);
      lvAh[d*72 + p8 + j] = hi;
      lvAl[d*72 + p8 + j] = f2bf(v - bf2f(hi));
    }
  }
  if(tid < 32) liqt[tid] = invn[b*256 + h*32 + tid] * t2;   // fold temp2 into qn
  __syncthreads();
  const int wave = tid >> 6, lane = tid & 63;
  const int lm = lane & 15, lq = lane >> 4;
  const int tokw = blockIdx.x*256 + wave*64;
  const u16* qb = qkvvT + ((size_t)b*512 + h*32)*32768;
  float iq[8];
  #pragma unroll
  for(int j=0;j<8;++j) iq[j] = liqt[lq*8+j];
  u16* PW = Pl + wave*1152 + lm*72;
  u16* ob = xsa + (((size_t)b*4 + h)*32)*32768;
  for(int nt=0; nt<4; ++nt){
    const int tok = tokw + nt*16 + lm;
    // B-frags: qn = q*invn*t2, hi/lo bf16
    union { u16 u[8]; bf16x8 v; } qh, ql;
    #pragma unroll
    for(int j=0;j<8;++j){
      float qv = bf2f(qb[(size_t)(lq*8+j)*32768 + tok]) * iq[j];
      u16 hi = f2bf(qv);
      qh.u[j] = hi;
      ql.u[j] = f2bf(qv - bf2f(hi));
    }
    // S^T fragments
    f32x4 accS[4];
    #pragma unroll
    for(int mt=0;mt<4;++mt){
      bf16x8 Ah = *(const bf16x8*)(lkAh + (mt*16+lm)*40 + lq*8);
      bf16x8 Al = *(const bf16x8*)(lkAl + (mt*16+lm)*40 + lq*8);
      f32x4 a = {};
      a = MFMA16(Ah, qh.v, a);
      a = MFMA16(Ah, ql.v, a);
      a = MFMA16(Al, qh.v, a);
      accS[mt] = a;
    }
    // softmax over p (16 in-lane x 4 lq-lanes)
    float mx = -1e30f;
    #pragma unroll
    for(int mt=0;mt<4;++mt)
      mx = fmaxf(mx, fmaxf(fmaxf(accS[mt][0],accS[mt][1]), fmaxf(accS[mt][2],accS[mt][3])));
    mx = fmaxf(mx, __shfl_xor(mx,16));
    mx = fmaxf(mx, __shfl_xor(mx,32));
    float pexp[4][4];
    float sum = 0.f;
    #pragma unroll
    for(int mt=0;mt<4;++mt)
      #pragma unroll
      for(int r=0;r<4;++r){ float e = __expf(accS[mt][r]-mx); pexp[mt][r]=e; sum+=e; }
    sum += __shfl_xor(sum,16);
    sum += __shfl_xor(sum,32);
    const float rinv = 1.0f/sum;
    // P -> per-wave LDS (row = token col lm, cols p)
    #pragma unroll
    for(int mt=0;mt<4;++mt){
      *(unsigned int*)(PW + mt*16 + lq*4)     = pk2(pexp[mt][0], pexp[mt][1]);
      *(unsigned int*)(PW + mt*16 + lq*4 + 2) = pk2(pexp[mt][2], pexp[mt][3]);
    }
    // PV: out^T = vp~ . P  (M=d32, N=tok, K=p64 in 2 steps)
    f32x4 accO[2] = {};
    #pragma unroll
    for(int ks=0;ks<2;++ks){
      bf16x8 Pb = *(const bf16x8*)(PW + ks*32 + lq*8);
      #pragma unroll
      for(int mt=0;mt<2;++mt){
        bf16x8 Avh = *(const bf16x8*)(lvAh + (mt*16+lm)*72 + ks*32 + lq*8);
        bf16x8 Avl = *(const bf16x8*)(lvAl + (mt*16+lm)*72 + ks*32 + lq*8);
        accO[mt] = MFMA16(Avh, Pb, accO[mt]);
        accO[mt] = MFMA16(Avl, Pb, accO[mt]);
      }
    }
    // write out^T: rows d, cols tok (xsa is [d][n])
    #pragma unroll
    for(int mt=0;mt<2;++mt)
      #pragma unroll
      for(int r=0;r<4;++r)
        ob[(size_t)(mt*16+lq*4+r)*32768 + tok] = f2bf(accO[mt][r]*rinv);
  }
}

// ============ K_conv v6: fused grouped 3x3x3 conv, z-tile 8 =====================
// FROZEN. r3: duration invariant under occupancy 31->47% => per-CU-pipe
// saturated. Next lever would be MFMA-ification (deferred).
#define CSX 36
#define CSZ 360            // 10*CSX
__global__ __launch_bounds__(256,6) void kconv(const u16* __restrict__ qkvvT, const float* __restrict__ W_eff,
                                               const float* __restrict__ bias_eff, u16* __restrict__ convo){
  __shared__ float lf[10*CSZ];   // 14,400 B
  const int zt = blockIdx.x >> 2, yt = blockIdx.x & 3;
  const int g = blockIdx.y, b = blockIdx.z;
  const int tid = threadIdx.x;
  const int z0 = zt << 3, y0 = yt << 3;
  const int lz = tid >> 5;                // output z (0..7)
  const int vy = (tid >> 2) & 7;
  const int x0 = (tid & 3) << 3;
  float acc[4][8];
  #pragma unroll
  for(int oc=0;oc<4;++oc)
    #pragma unroll
    for(int xi=0;xi<8;++xi) acc[oc][xi] = 0.f;
  const u16* qb = qkvvT + (size_t)b*512*32768;
  // staging: threads 0..99 each own one (z-row, y-row)
  const int sz = tid / 10, sy = tid - sz*10;
  const int gz = z0 + sz - 1, gy = y0 + sy - 1;
  const bool srow_ok = (tid < 100) && ((unsigned)gz < 32u) && ((unsigned)gy < 32u);
  float2* d2 = (float2*)&lf[sz*CSZ + sy*CSX];
  const float* Wgbase = W_eff + (size_t)(g*16)*108;

  for(int p=0;p<16;++p){
    __syncthreads();   // previous pass compute done
    if(tid < 100){
      if(srow_ok){
        const u16* src = qb + ((size_t)(p*32 + g))*32768 + gz*1024 + gy*32;
        float carry = 0.f;
        #pragma unroll
        for(int q=0;q<4;++q){
          bf16x8 v = *(const bf16x8*)(src + q*8);
          float w0=bf2f((u16)v[0]), w1=bf2f((u16)v[1]), w2=bf2f((u16)v[2]), w3=bf2f((u16)v[3]);
          float w4=bf2f((u16)v[4]), w5=bf2f((u16)v[5]), w6=bf2f((u16)v[6]), w7=bf2f((u16)v[7]);
          d2[q*4+0] = make_float2(carry, w0);
          d2[q*4+1] = make_float2(w1, w2);
          d2[q*4+2] = make_float2(w3, w4);
          d2[q*4+3] = make_float2(w5, w6);
          carry = w7;
        }
        d2[16] = make_float2(carry, 0.f);
      } else {
        #pragma unroll
        for(int i=0;i<17;++i) d2[i] = make_float2(0.f, 0.f);
      }
    }
    __syncthreads();
    const float* Wg = Wgbase + p*108;    // [kz3][ky3][kx3][oc4], wave-uniform
    #pragma unroll
    for(int dy=0;dy<3;++dy){
      #pragma unroll
      for(int dz=0;dz<3;++dz){
        const float* row = &lf[(lz+dz)*CSZ + (vy+dy)*CSX + x0];
        float4 fa = *(const float4*)(row);
        float4 fb = *(const float4*)(row+4);
        float2 fc = *(const float2*)(row+8);
        float fw[10] = {fa.x,fa.y,fa.z,fa.w, fb.x,fb.y,fb.z,fb.w, fc.x,fc.y};
        const float* Wb = Wg + (dz*3+dy)*12;
        #pragma unroll
        for(int kx=0;kx<3;++kx){
          float4 wv = *(const float4*)(Wb + kx*4);
          #pragma unroll
          for(int xi=0;xi<8;++xi){
            float f = fw[xi+kx];
            acc[0][xi] += wv.x*f; acc[1][xi] += wv.y*f;
            acc[2][xi] += wv.z*f; acc[3][xi] += wv.w*f;
          }
        }
      }
    }
  }
  const float4 bi = *(const float4*)(bias_eff + g*4);  // wave-uniform -> s_load
  const int nb = (z0 + lz)*1024 + (y0+vy)*32 + x0;
  u16* ob = convo + ((size_t)b*32768 + nb)*128 + g*4;
  #pragma unroll
  for(int xi=0;xi<8;++xi){
    unsigned long long pk = (unsigned long long)f2bf(acc[0][xi] + bi.x)
                          | ((unsigned long long)f2bf(acc[1][xi] + bi.y) << 16)
                          | ((unsigned long long)f2bf(acc[2][xi] + bi.z) << 32)
                          | ((unsigned long long)f2bf(acc[3][xi] + bi.w) << 48);
    *(unsigned long long*)(ob + (size_t)xi*128) = pk;
  }
}

// ============ K6: output assembly (SA gather-GEMM + CA GEMM + conv + rates), fp32 out
#define K6PAD 136
__global__ __launch_bounds__(256) void k6_out(const u16* __restrict__ qkvvT, const u16* __restrict__ xsa,
                                              const u16* __restrict__ conv, const u16* __restrict__ M2,
                                              const u16* __restrict__ Woutb, const float* __restrict__ bout,
                                              const float* __restrict__ bout2, const float* __restrict__ rate,
                                              const float* __restrict__ rate2, float* __restrict__ out){
  __shared__ u16 lA[128*K6PAD];
  const int tile = blockIdx.x;
  const int b  = tile >> 8;
  const int n0 = (tile & 255) << 7;
  const int tid = threadIdx.x;
  const int hh = (n0 >> 8) & 3;   // constant per 128-token tile
  const int dh = n0 >> 10;
  // ---- phase A: stage scrambled x_SA segment (contiguous!) -> lA[tok][c']
  const u16* xseg = xsa + (((size_t)b*4 + hh)*32 + dh)*32768 + ((size_t)(n0 & 255) << 7);
  {
    const int r = tid >> 1, off = (tid & 1) << 6;
    const u16* src = xseg + r*128 + off;
    u16* dst = &lA[r*K6PAD + off];
    #pragma unroll
    for(int q=0;q<8;++q) *(bf16x8*)(dst + q*8) = *(const bf16x8*)(src + q*8);
  }
  __syncthreads();
  const int wave = tid >> 6, lane = tid & 63;
  const int lm = lane & 15, lq = lane >> 4;
  f32x4 accS[2][4] = {};
  #pragma unroll
  for(int ks=0;ks<4;++ks){
    bf16x8 a0 = *(const bf16x8*)(&lA[(wave*32 + lm)*K6PAD + ks*32 + lq*8]);
    bf16x8 a1 = *(const bf16x8*)(&lA[(wave*32 + 16 + lm)*K6PAD + ks*32 + lq*8]);
    #pragma unroll
    for(int nt=0;nt<4;++nt){
      bf16x8 bw = *(const bf16x8*)(Woutb + (nt*16 + lm)*128 + ks*32 + lq*8);
      accS[0][nt] = MFMA16(a0, bw, accS[0][nt]);
      accS[1][nt] = MFMA16(a1, bw, accS[1][nt]);
    }
  }
  __syncthreads();
  // ---- phase B: stage v_CA tile transposed -> lA[tok][c'']
  {
    const int cb = tid >> 4, t8 = (tid & 15) << 3;
    const u16* vb = qkvvT + ((size_t)b*512 + 256)*32768 + n0;
    #pragma unroll
    for(int r2=0;r2<8;++r2){
      int c = cb + (r2<<4);
      bf16x8 v = *(const bf16x8*)(vb + (size_t)c*32768 + t8);
      #pragma unroll
      for(int j=0;j<8;++j) lA[(t8+j)*K6PAD + c] = (u16)v[j];
    }
  }
  __syncthreads();
  f32x4 accC[2][4] = {};
  #pragma unroll
  for(int ks=0;ks<4;++ks){
    bf16x8 a0 = *(const bf16x8*)(&lA[(wave*32 + lm)*K6PAD + ks*32 + lq*8]);
    bf16x8 a1 = *(const bf16x8*)(&lA[(wave*32 + 16 + lm)*K6PAD + ks*32 + lq*8]);
    #pragma unroll
    for(int nt=0;nt<4;++nt){
      bf16x8 bm = *(const bf16x8*)(M2 + ((size_t)b*64 + nt*16 + lm)*128 + ks*32 + lq*8);
      accC[0][nt] = MFMA16(a0, bm, accC[0][nt]);
      accC[1][nt] = MFMA16(a1, bm, accC[1][nt]);
    }
  }
  const float rt = rate[0], rt2 = rate2[0];
  float* ob = out + ((size_t)b*32768 + n0)*128;
  const u16* cbp = conv + ((size_t)b*32768 + n0)*128;
  #pragma unroll
  for(int mt=0;mt<2;++mt){
    #pragma unroll
    for(int r=0;r<4;++r){
      const int tok = wave*32 + mt*16 + lq*4 + r;
      #pragma unroll
      for(int nt=0;nt<4;++nt){
        const int j = nt*16 + lm;
        float sa = accS[mt][nt][r] + bout[j];
        float ca = accC[mt][nt][r] + bout2[j];
        float c1 = bf2f(cbp[(size_t)tok*128 + j]);
        float c2 = bf2f(cbp[(size_t)tok*128 + 64 + j]);
        ob[(size_t)tok*128 + j]      = rt*sa + rt2*c1;
        ob[(size_t)tok*128 + 64 + j] = rt*ca + rt2*c2;
      }
    }
  }
}

extern "C" void kernel_launch(void* const* d_in, const int* in_sizes, int n_in,
                              void* d_out, int out_size, void* d_ws, size_t ws_size,
                              hipStream_t stream){
  const float* x     = (const float*)d_in[0];
  const float* Wq    = (const float*)d_in[1];
  const float* Wfc   = (const float*)d_in[2];
  const float* bfc   = (const float*)d_in[3];
  const float* Wdep  = (const float*)d_in[4];
  const float* bdep  = (const float*)d_in[5];
  const float* WE    = (const float*)d_in[6];
  const float* bE    = (const float*)d_in[7];
  const float* temp  = (const float*)d_in[8];
  const float* temp2 = (const float*)d_in[9];
  const float* rate  = (const float*)d_in[10];
  const float* rate2 = (const float*)d_in[11];
  const float* Wout  = (const float*)d_in[12];
  const float* bout  = (const float*)d_in[13];
  const float* Wout2 = (const float*)d_in[14];
  const float* bout2 = (const float*)d_in[15];
  float* outp = (float*)d_out;

  char* w = (char*)d_ws;
  size_t off = 0;
  auto alloc = [&](size_t bytes)->char*{ char* p = w + off; off += (bytes + 255) & ~(size_t)255; return p; };
  u16*   qkvvT  = (u16*)  alloc((size_t)4*512*32768*2);   // 134 MB, channel-major
  u16*   xsa    = (u16*)  alloc((size_t)4*4*32*32768*2);  // 33.5 MB
  u16*   convb  = (u16*)  alloc((size_t)4*32768*128*2);   // 33.5 MB, token-major
  float* W_eff  = (float*)alloc(55296*4);
  float* biasef = (float*)alloc(128*4);
  float* invn   = (float*)alloc(1024*4);
  float* kp     = (float*)alloc(32768*4);
  float* vp     = (float*)alloc(32768*4);
  float* G      = (float*)alloc(16384*4);
  u16*   M2     = (u16*)  alloc(32768*2);
  u16*   WEb    = (u16*)  alloc((size_t)2097152*2);       // bf16 copies of MFMA weights
  u16*   Wqb    = (u16*)  alloc(65536*2);
  u16*   Woutb  = (u16*)  alloc(8192*2);

  // zero the fp32 atomic-accumulation buffers (kp|vp|G are contiguous)
  hipMemsetAsync(kp, 0, (size_t)(32768+32768+16384)*4, stream);

  kcvt3         <<<2120,          256, 0, stream>>>(WE, WEb, Wq, Wqb, Wout, Woutb);
  k1_qkvv       <<<1024,          256, 0, stream>>>(x, Wqb, qkvvT);
  k2_weff       <<<216,           256, 0, stream>>>(Wdep, Wfc, bdep, bfc, W_eff, biasef);
  k2b_norms     <<<1024,          256, 0, stream>>>(qkvvT, invn);
  k3_proj       <<<dim3(32,4,4),  256, 0, stream>>>(qkvvT, WEb, kp, vp);
  k4_gram       <<<dim3(64,4,4),   64, 0, stream>>>(qkvvT, G);
  k4b_softmax_m2<<<16,            256, 0, stream>>>(G, invn, temp, Wout2, M2);
  k5_xsa        <<<dim3(128,4,4), 256, 0, stream>>>(qkvvT, kp, vp, invn, bE, temp2, xsa);
  kconv         <<<dim3(16,32,4), 256, 0, stream>>>(qkvvT, W_eff, biasef, convb);
  k6_out        <<<1024,          256, 0, stream>>>(qkvvT, xsa, convb, M2, Woutb, bout, bout2, rate, rate2, outp);
}

// Round 6
// 540.844 us; speedup vs baseline: 1.3315x; 1.0285x over previous
//
#include <hip/hip_runtime.h>
#include <hip/hip_bf16.h>

typedef unsigned short u16;
typedef __attribute__((ext_vector_type(8))) short bf16x8;
typedef __attribute__((ext_vector_type(4))) float f32x4;

#define MFMA16(a,b,c) __builtin_amdgcn_mfma_f32_16x16x32_bf16((a),(b),(c),0,0,0)

__device__ __forceinline__ float bf2f(u16 u){ union{unsigned int i; float f;} v; v.i=((unsigned int)u)<<16; return v.f; }
__device__ __forceinline__ u16 f2bf(float f){ union{float f; unsigned int i;} v; v.f=f; unsigned int r=v.i+0x7fffu+((v.i>>16)&1u); return (u16)(r>>16); }
__device__ __forceinline__ unsigned int pk2(float a, float b){
  __hip_bfloat162 h = __float22bfloat162_rn(make_float2(a,b));
  union{ __hip_bfloat162 h; unsigned int u; } v; v.h = h; return v.u;
}

// ============ K0: fp32 -> bf16 conversions for the 3 MFMA weights, one launch ====
__global__ __launch_bounds__(256) void kcvt3(const float* __restrict__ WE, u16* __restrict__ WEb,
                                             const float* __restrict__ Wq, u16* __restrict__ Wqb,
                                             const float* __restrict__ Wo, u16* __restrict__ Wob){
  int bid = blockIdx.x;
  const float* src; u16* dst; int base;
  if(bid < 2048){ src = WE; dst = WEb; base = bid*1024; }
  else if(bid < 2112){ src = Wq; dst = Wqb; base = (bid-2048)*1024; }
  else { src = Wo; dst = Wob; base = (bid-2112)*1024; }
  int i = base + threadIdx.x*4;
  float4 v = *(const float4*)(src + i);
  ushort4 o; o.x = f2bf(v.x); o.y = f2bf(v.y); o.z = f2bf(v.z); o.w = f2bf(v.w);
  *(ushort4*)(dst + i) = o;
}

// ================= K1: qkvvT[b][oc][n] = sum_c Wq[oc][c]*x[b][c][n] (MFMA) =========
#define K1PAD 136
__global__ __launch_bounds__(256) void k1_qkvv(const float* __restrict__ x, const u16* __restrict__ Wqb, u16* __restrict__ qkvvT){
  __shared__ u16 lB[128*K1PAD];
  const int tile = blockIdx.x;            // b*256 + token tile
  const int b  = tile >> 8;
  const int n0 = (tile & 255) << 7;
  const int tid = threadIdx.x;
  const float* xb = x + (size_t)b*128*32768;
  {
    const int cb = (tid >> 4) << 1;       // even channel 0..30
    const int m  = tid & 15;
    const int t8 = m << 3;                // 8-token block
    const int swz = (m & 3) << 3;         // rotation amount (u16 units)
    unsigned int* basep = (unsigned int*)lB;
    #pragma unroll
    for(int r=0;r<4;++r){
      const int c = cb + (r<<5);
      const float4* p0 = (const float4*)(xb + (size_t)c*32768 + n0 + t8);
      const float4* p1 = (const float4*)(xb + (size_t)(c+1)*32768 + n0 + t8);
      float4 a0 = p0[0], a1 = p0[1];
      float4 b0 = p1[0], b1 = p1[1];
      const int rot = (swz + c) & 127;    // rotation keeps everything inside the row
      int di = t8*68 + (rot>>1);
      basep[di      ] = pk2(a0.x, b0.x);
      basep[di+  68 ] = pk2(a0.y, b0.y);
      basep[di+ 136 ] = pk2(a0.z, b0.z);
      basep[di+ 204 ] = pk2(a0.w, b0.w);
      basep[di+ 272 ] = pk2(a1.x, b1.x);
      basep[di+ 340 ] = pk2(a1.y, b1.y);
      basep[di+ 408 ] = pk2(a1.z, b1.z);
      basep[di+ 476 ] = pk2(a1.w, b1.w);
    }
  }
  __syncthreads();
  const int wave = tid >> 6, lane = tid & 63;
  const int wm = (wave & 1) << 6;   // oc half
  const int wn = (wave >> 1) << 6;  // token half
  const int lm = lane & 15, lq = lane >> 4;
  u16* outb = qkvvT + (size_t)b*512*32768;
  for(int s=0;s<4;++s){
    const int oc0 = s << 7;
    f32x4 acc[4][4] = {};
    const u16* Arow = Wqb + (oc0 + wm + lm)*128 + lq*8;
    #pragma unroll
    for(int ks=0; ks<4; ++ks){
      bf16x8 af[4], bfr[4];
      #pragma unroll
      for(int mt=0;mt<4;++mt) af[mt] = *(const bf16x8*)(Arow + mt*2048 + ks*32);
      #pragma unroll
      for(int nt=0;nt<4;++nt){
        const int tr = wn + nt*16 + lm;
        const int rot = ((((tr>>3)&3)<<3) + ks*32 + lq*8) & 127;
        bfr[nt] = *(const bf16x8*)(&lB[tr*K1PAD + rot]);
      }
      #pragma unroll
      for(int mt=0;mt<4;++mt)
        #pragma unroll
        for(int nt=0;nt<4;++nt)
          acc[mt][nt] = MFMA16(af[mt], bfr[nt], acc[mt][nt]);
    }
    #pragma unroll
    for(int mt=0;mt<4;++mt){
      const int ocr = oc0 + wm + mt*16 + lq*4;
      #pragma unroll
      for(int nt=0;nt<4;++nt){
        const int n = n0 + wn + nt*16 + lm;
        #pragma unroll
        for(int r=0;r<4;++r) outb[(size_t)(ocr+r)*32768 + n] = f2bf(acc[mt][nt][r]);
      }
    }
  }
}

// ============ K2: fold fc(1x1) into depthwise-grouped conv weights (fp32 in) ======
// W_eff layout: [g 32][j 16][k 27][ol 4] fp32 ; oc = g*4+ol
__global__ void k2_weff(const float* __restrict__ Wdep, const float* __restrict__ Wfc,
                        const float* __restrict__ bdep, const float* __restrict__ bfc,
                        float* __restrict__ W_eff, float* __restrict__ bias_eff){
  int idx = blockIdx.x*256 + threadIdx.x;
  if(idx < 55296){
    int ol = idx & 3;
    int k  = (idx >> 2) % 27;
    int j  = (idx / 108) & 15;
    int g  = idx / 1728;
    int oc = g*4 + ol;
    float s = 0.f;
    for(int o=0;o<16;++o) s += Wdep[(oc*16 + o)*27 + k] * Wfc[o*16 + j];
    W_eff[idx] = s;
  }
  if(idx < 128){
    float s = bdep[idx];
    for(int o=0;o<16;++o){
      float wsum = 0.f;
      for(int k=0;k<27;++k) wsum += Wdep[(idx*16 + o)*27 + k];
      s += wsum * bfc[o];  // b_fc == 0 in this problem (boundary fold vacuous)
    }
    bias_eff[idx] = s;
  }
}

// ============ KMEGA: kconv + k2b(norms) + k3(proj) + k4(gram) in ONE launch ======
// Roles by blockIdx: groups of 15 = 8 kconv + 7 other (512 k3, 256 k4, 1024 k2b),
// interleaved so every CU hosts a pipe-complementary mix for the whole duration.
// Rationale (r3/r5 counters): kconv true-VALU ~40% (78% shown / gfx94x 2x
// inflation), MFMA pipe 0%, and r3 showed homogeneous occupancy doesn't help.
// k2b/k3/k4 are VMEM/MFMA-bound -> they fill kconv's idle issue slots, removing
// ~50-60 us of serial launches. kconv body byte-preserved (codegen knife edge).
#define CSX 36
#define CSZ 360            // 10*CSX
__global__ __launch_bounds__(256,6) void kmega(const u16* __restrict__ qkvvT, const float* __restrict__ W_eff,
                                               const float* __restrict__ bias_eff, u16* __restrict__ convo,
                                               const u16* __restrict__ WEb, float* __restrict__ kp,
                                               float* __restrict__ vp, float* __restrict__ G,
                                               float* __restrict__ invn){
  __shared__ float lf[10*CSZ];   // 14,400 B (kconv role)
  __shared__ float wsum[4];      // k2b role
  const int bid = blockIdx.x;
  const int gq = bid / 15, rr = bid - gq*15;
  const int tid = threadIdx.x;

  if(rr < 8){
    // ---------------- kconv role (cidx 0..2047) ----------------
    const int cidx = gq*8 + rr;
    const int gx = cidx & 15, g = (cidx>>4)&31, b = cidx>>9;
    const int zt = gx >> 2, yt = gx & 3;
    const int z0 = zt << 3, y0 = yt << 3;
    const int lz = tid >> 5;                // output z (0..7)
    const int vy = (tid >> 2) & 7;
    const int x0 = (tid & 3) << 3;
    float acc[4][8];
    #pragma unroll
    for(int oc=0;oc<4;++oc)
      #pragma unroll
      for(int xi=0;xi<8;++xi) acc[oc][xi] = 0.f;
    const u16* qb = qkvvT + (size_t)b*512*32768;
    const int sz = tid / 10, sy = tid - sz*10;
    const int gz = z0 + sz - 1, gy = y0 + sy - 1;
    const bool srow_ok = (tid < 100) && ((unsigned)gz < 32u) && ((unsigned)gy < 32u);
    float2* d2 = (float2*)&lf[sz*CSZ + sy*CSX];
    const float* Wgbase = W_eff + (size_t)(g*16)*108;

    for(int p=0;p<16;++p){
      __syncthreads();   // previous pass compute done
      if(tid < 100){
        if(srow_ok){
          const u16* src = qb + ((size_t)(p*32 + g))*32768 + gz*1024 + gy*32;
          float carry = 0.f;
          #pragma unroll
          for(int q=0;q<4;++q){
            bf16x8 v = *(const bf16x8*)(src + q*8);
            float w0=bf2f((u16)v[0]), w1=bf2f((u16)v[1]), w2=bf2f((u16)v[2]), w3=bf2f((u16)v[3]);
            float w4=bf2f((u16)v[4]), w5=bf2f((u16)v[5]), w6=bf2f((u16)v[6]), w7=bf2f((u16)v[7]);
            d2[q*4+0] = make_float2(carry, w0);
            d2[q*4+1] = make_float2(w1, w2);
            d2[q*4+2] = make_float2(w3, w4);
            d2[q*4+3] = make_float2(w5, w6);
            carry = w7;
          }
          d2[16] = make_float2(carry, 0.f);
        } else {
          #pragma unroll
          for(int i=0;i<17;++i) d2[i] = make_float2(0.f, 0.f);
        }
      }
      __syncthreads();
      const float* Wg = Wgbase + p*108;    // [kz3][ky3][kx3][oc4], wave-uniform
      #pragma unroll
      for(int dy=0;dy<3;++dy){
        #pragma unroll
        for(int dz=0;dz<3;++dz){
          const float* row = &lf[(lz+dz)*CSZ + (vy+dy)*CSX + x0];
          float4 fa = *(const float4*)(row);
          float4 fb = *(const float4*)(row+4);
          float2 fc = *(const float2*)(row+8);
          float fw[10] = {fa.x,fa.y,fa.z,fa.w, fb.x,fb.y,fb.z,fb.w, fc.x,fc.y};
          const float* Wb = Wg + (dz*3+dy)*12;
          #pragma unroll
          for(int kx=0;kx<3;++kx){
            float4 wv = *(const float4*)(Wb + kx*4);
            #pragma unroll
            for(int xi=0;xi<8;++xi){
              float f = fw[xi+kx];
              acc[0][xi] += wv.x*f; acc[1][xi] += wv.y*f;
              acc[2][xi] += wv.z*f; acc[3][xi] += wv.w*f;
            }
          }
        }
      }
    }
    const float4 bi = *(const float4*)(bias_eff + g*4);  // wave-uniform -> s_load
    const int nb = (z0 + lz)*1024 + (y0+vy)*32 + x0;
    u16* ob = convo + ((size_t)b*32768 + nb)*128 + g*4;
    #pragma unroll
    for(int xi=0;xi<8;++xi){
      unsigned long long pk = (unsigned long long)f2bf(acc[0][xi] + bi.x)
                            | ((unsigned long long)f2bf(acc[1][xi] + bi.y) << 16)
                            | ((unsigned long long)f2bf(acc[2][xi] + bi.z) << 32)
                            | ((unsigned long long)f2bf(acc[3][xi] + bi.w) << 48);
      *(unsigned long long*)(ob + (size_t)xi*128) = pk;
    }
    return;
  }

  const int oidx = gq*7 + (rr - 8);   // 0..1791
  if(oidx < 512){
    // ---------------- k3 role: k_proj / v_SA_proj ----------------
    const int kc = oidx & 31;
    const int b  = (oidx >> 5) & 3;
    const int zz = oidx >> 7;             // 0..3
    const int ts = zz >> 1;
    const int rh = (zz & 1) << 6;
    const int wave = tid >> 6, lane = tid & 63;
    const int lm = lane & 15, lq = lane >> 4;
    const int coff = ts ? 384 : 128;
    const u16* Arow = qkvvT + ((size_t)b*512 + coff + rh + wave*16 + lm)*32768 + kc*1024 + lq*8;
    f32x4 acc[4] = {};
    for(int ks=0; ks<32; ++ks){
      bf16x8 af = *(const bf16x8*)(Arow + ks*32);
      #pragma unroll
      for(int nt=0;nt<4;++nt){
        bf16x8 bfr = *(const bf16x8*)(WEb + (size_t)(nt*16 + lm)*32768 + kc*1024 + ks*32 + lq*8);
        acc[nt] = MFMA16(af, bfr, acc[nt]);
      }
    }
    float* out = (ts ? vp : kp) + (size_t)b*128*64;
    const int r0 = rh + wave*16 + lq*4;
    #pragma unroll
    for(int nt=0;nt<4;++nt){
      const int p = nt*16 + lm;
      #pragma unroll
      for(int r=0;r<4;++r) atomicAdd(&out[(r0+r)*64 + p], acc[nt][r]);
    }
  } else if(oidx < 768){
    // ---------------- k4 role: Gram, one kc chunk per wave ----------------
    const int idx2 = oidx - 512;          // 0..255
    const int h = idx2 & 3, b = (idx2>>2)&3, kcg = idx2 >> 4;   // kcg 0..15
    const int wave = tid >> 6, lane = tid & 63;
    const int kc = kcg*4 + wave;          // 0..63
    const int lm = lane & 15, lq = lane >> 4;
    const u16* qb = qkvvT + ((size_t)b*512 + h*32)*32768 + kc*512 + lq*8;
    const u16* kb = qb + (size_t)128*32768;
    f32x4 acc[2][2] = {};
    for(int ks=0; ks<16; ++ks){
      bf16x8 af[2], bfr[2];
      af[0]  = *(const bf16x8*)(qb + (size_t)lm*32768 + ks*32);
      af[1]  = *(const bf16x8*)(qb + (size_t)(16+lm)*32768 + ks*32);
      bfr[0] = *(const bf16x8*)(kb + (size_t)lm*32768 + ks*32);
      bfr[1] = *(const bf16x8*)(kb + (size_t)(16+lm)*32768 + ks*32);
      #pragma unroll
      for(int mt=0;mt<2;++mt)
        #pragma unroll
        for(int nt=0;nt<2;++nt) acc[mt][nt] = MFMA16(af[mt], bfr[nt], acc[mt][nt]);
    }
    float* Gb = G + (size_t)(b*4 + h)*1024;
    #pragma unroll
    for(int mt=0;mt<2;++mt)
      #pragma unroll
      for(int nt=0;nt<2;++nt)
        #pragma unroll
        for(int r=0;r<4;++r){
          int d = mt*16 + lq*4 + r, e = nt*16 + lm;
          atomicAdd(&Gb[d*32 + e], acc[mt][nt][r]);
        }
  } else {
    // ---------------- k2b role: inverse l2 norms ----------------
    const int idx4 = oidx - 768;          // 0..1023
    const int b = idx4 >> 8, c = idx4 & 255;
    const u16* row = qkvvT + ((size_t)b*512 + c)*32768;
    float s = 0.f;
    for(int n = tid*8; n < 32768; n += 2048){
      bf16x8 v = *(const bf16x8*)(row + n);
      #pragma unroll
      for(int j=0;j<8;++j){ float f = bf2f((u16)v[j]); s += f*f; }
    }
    for(int off=32; off; off>>=1) s += __shfl_down(s, off, 64);
    if((tid & 63)==0) wsum[tid>>6] = s;
    __syncthreads();
    if(tid==0){
      float t = wsum[0]+wsum[1]+wsum[2]+wsum[3];
      invn[idx4] = 1.0f / fmaxf(sqrtf(t), 1e-12f);
    }
  }
}

// ============ K4b: scale+softmax(attn_CA) then M2 = W_out2 * attn_CA =============
__global__ __launch_bounds__(256) void k4b_softmax_m2(const float* __restrict__ G, const float* __restrict__ invn,
                                                      const float* __restrict__ temp, const float* __restrict__ Wout2,
                                                      u16* __restrict__ M2){
  const int b = blockIdx.x >> 2, h = blockIdx.x & 3;
  __shared__ float A[32][33];
  const float* Gb = G + (size_t)(b*4 + h)*1024;
  const float* inb = invn + b*256;
  const float th = temp[h];
  const int tid = threadIdx.x;
  if(tid < 32){
    const int d = tid;
    const float iq = inb[h*32 + d];
    float row[32]; float mx = -1e30f;
    #pragma unroll
    for(int e=0;e<32;++e){
      float v = Gb[d*32+e] * iq * inb[128 + h*32 + e] * th;
      row[e] = v; mx = fmaxf(mx, v);
    }
    float s = 0.f;
    #pragma unroll
    for(int e=0;e<32;++e){ float ee = __expf(row[e]-mx); row[e] = ee; s += ee; }
    const float rs = 1.0f/s;
    #pragma unroll
    for(int e=0;e<32;++e) A[d][e] = row[e]*rs;
  }
  __syncthreads();
  for(int o = tid; o < 2048; o += 256){
    const int j = o >> 5, e = o & 31;
    float s = 0.f;
    #pragma unroll
    for(int d=0;d<32;++d) s += Wout2[j*128 + h*32 + d] * A[d][e];
    M2[((size_t)b*64 + j)*128 + h*32 + e] = f2bf(s);
  }
}

// ============ K5 v3: Linformer attention via MFMA ================================
__global__ __launch_bounds__(256) void k5_xsa(const u16* __restrict__ qkvvT, const float* __restrict__ kp,
                                              const float* __restrict__ vp, const float* __restrict__ invn,
                                              const float* __restrict__ bE, const float* __restrict__ temp2,
                                              u16* __restrict__ xsa){
  __shared__ __align__(16) u16 L[14336];
  __shared__ float liqt[32];
  u16* lkAh = L;            // [64][40] : kp^T + bE, hi
  u16* lkAl = L + 2560;     // lo
  u16* lvAh = L + 5120;     // [32][72] : vp + bE, hi
  u16* lvAl = L + 7424;     // lo
  u16* Pl   = L + 9728;     // [4 waves][16][72] per-wave P bounce
  const int b = blockIdx.z, h = blockIdx.y;
  const int tid = threadIdx.x;
  const float t2 = temp2[h];
  {  // stage lkA = kp^T + bE (hi/lo)
    const int p = tid >> 2, d8 = (tid & 3) << 3;
    const float be = bE[p];
    const float* kpb = kp + ((size_t)b*128 + h*32)*64;
    #pragma unroll
    for(int j=0;j<8;++j){
      float v = kpb[(size_t)(d8+j)*64 + p] + be;
      u16 hi = f2bf(v);
      lkAh[p*40 + d8 + j] = hi;
      lkAl[p*40 + d8 + j] = f2bf(v - bf2f(hi));
    }
  }
  {  // stage lvA = vp + bE (hi/lo)
    const int d = tid >> 3, p8 = (tid & 7) << 3;
    const float* vpb = vp + ((size_t)b*128 + h*32)*64;
    #pragma unroll
    for(int j=0;j<8;++j){
      float v = vpb[(size_t)d*64 + p8 + j] + bE[p8+j];
      u16 hi = f2bf(v);
      lvAh[d*72 + p8 + j] = hi;
      lvAl[d*72 + p8 + j] = f2bf(v - bf2f(hi));
    }
  }
  if(tid < 32) liqt[tid] = invn[b*256 + h*32 + tid] * t2;   // fold temp2 into qn
  __syncthreads();
  const int wave = tid >> 6, lane = tid & 63;
  const int lm = lane & 15, lq = lane >> 4;
  const int tokw = blockIdx.x*256 + wave*64;
  const u16* qb = qkvvT + ((size_t)b*512 + h*32)*32768;
  float iq[8];
  #pragma unroll
  for(int j=0;j<8;++j) iq[j] = liqt[lq*8+j];
  u16* PW = Pl + wave*1152 + lm*72;
  u16* ob = xsa + (((size_t)b*4 + h)*32)*32768;
  for(int nt=0; nt<4; ++nt){
    const int tok = tokw + nt*16 + lm;
    union { u16 u[8]; bf16x8 v; } qh, ql;
    #pragma unroll
    for(int j=0;j<8;++j){
      float qv = bf2f(qb[(size_t)(lq*8+j)*32768 + tok]) * iq[j];
      u16 hi = f2bf(qv);
      qh.u[j] = hi;
      ql.u[j] = f2bf(qv - bf2f(hi));
    }
    f32x4 accS[4];
    #pragma unroll
    for(int mt=0;mt<4;++mt){
      bf16x8 Ah = *(const bf16x8*)(lkAh + (mt*16+lm)*40 + lq*8);
      bf16x8 Al = *(const bf16x8*)(lkAl + (mt*16+lm)*40 + lq*8);
      f32x4 a = {};
      a = MFMA16(Ah, qh.v, a);
      a = MFMA16(Ah, ql.v, a);
      a = MFMA16(Al, qh.v, a);
      accS[mt] = a;
    }
    float mx = -1e30f;
    #pragma unroll
    for(int mt=0;mt<4;++mt)
      mx = fmaxf(mx, fmaxf(fmaxf(accS[mt][0],accS[mt][1]), fmaxf(accS[mt][2],accS[mt][3])));
    mx = fmaxf(mx, __shfl_xor(mx,16));
    mx = fmaxf(mx, __shfl_xor(mx,32));
    float pexp[4][4];
    float sum = 0.f;
    #pragma unroll
    for(int mt=0;mt<4;++mt)
      #pragma unroll
      for(int r=0;r<4;++r){ float e = __expf(accS[mt][r]-mx); pexp[mt][r]=e; sum+=e; }
    sum += __shfl_xor(sum,16);
    sum += __shfl_xor(sum,32);
    const float rinv = 1.0f/sum;
    #pragma unroll
    for(int mt=0;mt<4;++mt){
      *(unsigned int*)(PW + mt*16 + lq*4)     = pk2(pexp[mt][0], pexp[mt][1]);
      *(unsigned int*)(PW + mt*16 + lq*4 + 2) = pk2(pexp[mt][2], pexp[mt][3]);
    }
    f32x4 accO[2] = {};
    #pragma unroll
    for(int ks=0;ks<2;++ks){
      bf16x8 Pb = *(const bf16x8*)(PW + ks*32 + lq*8);
      #pragma unroll
      for(int mt=0;mt<2;++mt){
        bf16x8 Avh = *(const bf16x8*)(lvAh + (mt*16+lm)*72 + ks*32 + lq*8);
        bf16x8 Avl = *(const bf16x8*)(lvAl + (mt*16+lm)*72 + ks*32 + lq*8);
        accO[mt] = MFMA16(Avh, Pb, accO[mt]);
        accO[mt] = MFMA16(Avl, Pb, accO[mt]);
      }
    }
    #pragma unroll
    for(int mt=0;mt<2;++mt)
      #pragma unroll
      for(int r=0;r<4;++r)
        ob[(size_t)(mt*16+lq*4+r)*32768 + tok] = f2bf(accO[mt][r]*rinv);
  }
}

// ============ K6: output assembly (SA gather-GEMM + CA GEMM + conv + rates), fp32 out
#define K6PAD 136
__global__ __launch_bounds__(256) void k6_out(const u16* __restrict__ qkvvT, const u16* __restrict__ xsa,
                                              const u16* __restrict__ conv, const u16* __restrict__ M2,
                                              const u16* __restrict__ Woutb, const float* __restrict__ bout,
                                              const float* __restrict__ bout2, const float* __restrict__ rate,
                                              const float* __restrict__ rate2, float* __restrict__ out){
  __shared__ u16 lA[128*K6PAD];
  const int tile = blockIdx.x;
  const int b  = tile >> 8;
  const int n0 = (tile & 255) << 7;
  const int tid = threadIdx.x;
  const int hh = (n0 >> 8) & 3;   // constant per 128-token tile
  const int dh = n0 >> 10;
  // ---- phase A: stage scrambled x_SA segment (contiguous!) -> lA[tok][c']
  const u16* xseg = xsa + (((size_t)b*4 + hh)*32 + dh)*32768 + ((size_t)(n0 & 255) << 7);
  {
    const int r = tid >> 1, off = (tid & 1) << 6;
    const u16* src = xseg + r*128 + off;
    u16* dst = &lA[r*K6PAD + off];
    #pragma unroll
    for(int q=0;q<8;++q) *(bf16x8*)(dst + q*8) = *(const bf16x8*)(src + q*8);
  }
  __syncthreads();
  const int wave = tid >> 6, lane = tid & 63;
  const int lm = lane & 15, lq = lane >> 4;
  f32x4 accS[2][4] = {};
  #pragma unroll
  for(int ks=0;ks<4;++ks){
    bf16x8 a0 = *(const bf16x8*)(&lA[(wave*32 + lm)*K6PAD + ks*32 + lq*8]);
    bf16x8 a1 = *(const bf16x8*)(&lA[(wave*32 + 16 + lm)*K6PAD + ks*32 + lq*8]);
    #pragma unroll
    for(int nt=0;nt<4;++nt){
      bf16x8 bw = *(const bf16x8*)(Woutb + (nt*16 + lm)*128 + ks*32 + lq*8);
      accS[0][nt] = MFMA16(a0, bw, accS[0][nt]);
      accS[1][nt] = MFMA16(a1, bw, accS[1][nt]);
    }
  }
  __syncthreads();
  // ---- phase B: stage v_CA tile transposed -> lA[tok][c'']
  {
    const int cb = tid >> 4, t8 = (tid & 15) << 3;
    const u16* vb = qkvvT + ((size_t)b*512 + 256)*32768 + n0;
    #pragma unroll
    for(int r2=0;r2<8;++r2){
      int c = cb + (r2<<4);
      bf16x8 v = *(const bf16x8*)(vb + (size_t)c*32768 + t8);
      #pragma unroll
      for(int j=0;j<8;++j) lA[(t8+j)*K6PAD + c] = (u16)v[j];
    }
  }
  __syncthreads();
  f32x4 accC[2][4] = {};
  #pragma unroll
  for(int ks=0;ks<4;++ks){
    bf16x8 a0 = *(const bf16x8*)(&lA[(wave*32 + lm)*K6PAD + ks*32 + lq*8]);
    bf16x8 a1 = *(const bf16x8*)(&lA[(wave*32 + 16 + lm)*K6PAD + ks*32 + lq*8]);
    #pragma unroll
    for(int nt=0;nt<4;++nt){
      bf16x8 bm = *(const bf16x8*)(M2 + ((size_t)b*64 + nt*16 + lm)*128 + ks*32 + lq*8);
      accC[0][nt] = MFMA16(a0, bm, accC[0][nt]);
      accC[1][nt] = MFMA16(a1, bm, accC[1][nt]);
    }
  }
  const float rt = rate[0], rt2 = rate2[0];
  float* ob = out + ((size_t)b*32768 + n0)*128;
  const u16* cbp = conv + ((size_t)b*32768 + n0)*128;
  #pragma unroll
  for(int mt=0;mt<2;++mt){
    #pragma unroll
    for(int r=0;r<4;++r){
      const int tok = wave*32 + mt*16 + lq*4 + r;
      #pragma unroll
      for(int nt=0;nt<4;++nt){
        const int j = nt*16 + lm;
        float sa = accS[mt][nt][r] + bout[j];
        float ca = accC[mt][nt][r] + bout2[j];
        float c1 = bf2f(cbp[(size_t)tok*128 + j]);
        float c2 = bf2f(cbp[(size_t)tok*128 + 64 + j]);
        ob[(size_t)tok*128 + j]      = rt*sa + rt2*c1;
        ob[(size_t)tok*128 + 64 + j] = rt*ca + rt2*c2;
      }
    }
  }
}

extern "C" void kernel_launch(void* const* d_in, const int* in_sizes, int n_in,
                              void* d_out, int out_size, void* d_ws, size_t ws_size,
                              hipStream_t stream){
  const float* x     = (const float*)d_in[0];
  const float* Wq    = (const float*)d_in[1];
  const float* Wfc   = (const float*)d_in[2];
  const float* bfc   = (const float*)d_in[3];
  const float* Wdep  = (const float*)d_in[4];
  const float* bdep  = (const float*)d_in[5];
  const float* WE    = (const float*)d_in[6];
  const float* bE    = (const float*)d_in[7];
  const float* temp  = (const float*)d_in[8];
  const float* temp2 = (const float*)d_in[9];
  const float* rate  = (const float*)d_in[10];
  const float* rate2 = (const float*)d_in[11];
  const float* Wout  = (const float*)d_in[12];
  const float* bout  = (const float*)d_in[13];
  const float* Wout2 = (const float*)d_in[14];
  const float* bout2 = (const float*)d_in[15];
  float* outp = (float*)d_out;

  char* w = (char*)d_ws;
  size_t off = 0;
  auto alloc = [&](size_t bytes)->char*{ char* p = w + off; off += (bytes + 255) & ~(size_t)255; return p; };
  u16*   qkvvT  = (u16*)  alloc((size_t)4*512*32768*2);   // 134 MB, channel-major
  u16*   xsa    = (u16*)  alloc((size_t)4*4*32*32768*2);  // 33.5 MB
  u16*   convb  = (u16*)  alloc((size_t)4*32768*128*2);   // 33.5 MB, token-major
  float* W_eff  = (float*)alloc(55296*4);
  float* biasef = (float*)alloc(128*4);
  float* invn   = (float*)alloc(1024*4);
  float* kp     = (float*)alloc(32768*4);
  float* vp     = (float*)alloc(32768*4);
  float* G      = (float*)alloc(16384*4);
  u16*   M2     = (u16*)  alloc(32768*2);
  u16*   WEb    = (u16*)  alloc((size_t)2097152*2);       // bf16 copies of MFMA weights
  u16*   Wqb    = (u16*)  alloc(65536*2);
  u16*   Woutb  = (u16*)  alloc(8192*2);

  // zero the fp32 atomic-accumulation buffers (kp|vp|G are contiguous)
  hipMemsetAsync(kp, 0, (size_t)(32768+32768+16384)*4, stream);

  kcvt3         <<<2120,          256, 0, stream>>>(WE, WEb, Wq, Wqb, Wout, Woutb);
  k1_qkvv       <<<1024,          256, 0, stream>>>(x, Wqb, qkvvT);
  k2_weff       <<<216,           256, 0, stream>>>(Wdep, Wfc, bdep, bfc, W_eff, biasef);
  kmega         <<<3840,          256, 0, stream>>>(qkvvT, W_eff, biasef, convb, WEb, kp, vp, G, invn);
  k4b_softmax_m2<<<16,            256, 0, stream>>>(G, invn, temp, Wout2, M2);
  k5_xsa        <<<dim3(128,4,4), 256, 0, stream>>>(qkvvT, kp, vp, invn, bE, temp2, xsa);
  k6_out        <<<1024,          256, 0, stream>>>(qkvvT, xsa, convb, M2, Woutb, bout, bout2, rate, rate2, outp);
}